// Round 7
// baseline (331.391 us; speedup 1.0000x reference)
//
#include <hip/hip_runtime.h>
#include <hip/hip_bf16.h>
#include <stdint.h>

// ---------------- types / helpers ----------------
typedef __bf16 b16x8 __attribute__((ext_vector_type(8)));
typedef float  f32x4 __attribute__((ext_vector_type(4)));

__device__ __forceinline__ unsigned short f2bf(float f) {
    uint32_t u = __float_as_uint(f);
    u += 0x7fffu + ((u >> 16) & 1u);   // RNE
    return (unsigned short)(u >> 16);
}
__device__ __forceinline__ float bf2f(unsigned short s) {
    return __uint_as_float(((uint32_t)s) << 16);
}

__device__ __forceinline__ void gld16(const unsigned short* g, unsigned short* l) {
    __builtin_amdgcn_global_load_lds(
        (const __attribute__((address_space(1))) void*)g,
        (__attribute__((address_space(3))) void*)l, 16, 0, 0);
}

// ---------------- input dtype detection ----------------
__global__ void k_detect(const unsigned short* __restrict__ q, int n, int* __restrict__ flag) {
    float m = 0.f;
    for (int i = threadIdx.x; i < n; i += 256) {
        float f = fabsf(bf2f(q[i]));
        if (!(f < 1e30f)) f = 1e30f;
        m = fmaxf(m, f);
    }
#pragma unroll
    for (int o = 32; o > 0; o >>= 1) m = fmaxf(m, __shfl_xor(m, o));
    __shared__ float red[4];
    if ((threadIdx.x & 63) == 0) red[threadIdx.x >> 6] = m;
    __syncthreads();
    if (threadIdx.x == 0) {
        m = fmaxf(fmaxf(red[0], red[1]), fmaxf(red[2], red[3]));
        flag[0] = (m > 1e6f) ? 1 : 0;   // 1 => inputs are f32
    }
}

// ---------------- f32/bf16 -> bf16 materialization (8 elems / thread) ------
__global__ __launch_bounds__(256) void k_cvt(const void* __restrict__ src,
                                             unsigned short* __restrict__ dst,
                                             long n8, const int* __restrict__ flag) {
    long i = blockIdx.x * 256L + threadIdx.x;
    long stride = (long)gridDim.x * 256L;
    if (flag[0]) {
        const float4* s = (const float4*)src;
        for (long j = i; j < n8; j += stride) {
            float4 a = s[2 * j], b = s[2 * j + 1];
            uint4 o;
            o.x = f2bf(a.x) | ((uint32_t)f2bf(a.y) << 16);
            o.y = f2bf(a.z) | ((uint32_t)f2bf(a.w) << 16);
            o.z = f2bf(b.x) | ((uint32_t)f2bf(b.y) << 16);
            o.w = f2bf(b.z) | ((uint32_t)f2bf(b.w) << 16);
            ((uint4*)dst)[j] = o;
        }
    } else {
        const uint4* s = (const uint4*)src;
        for (long j = i; j < n8; j += stride) ((uint4*)dst)[j] = s[j];
    }
}

// biases -> f32 (4 x 1024)
__global__ __launch_bounds__(256) void k_cvt_bias(const void* b0, const void* b1,
                                                  const void* b2, const void* b3,
                                                  float* __restrict__ dst,
                                                  const int* __restrict__ flag) {
    int i = blockIdx.x * 256 + threadIdx.x;   // 4096 threads
    int which = i >> 10, idx = i & 1023;
    const void* src = (which == 0) ? b0 : (which == 1) ? b1 : (which == 2) ? b2 : b3;
    dst[i] = flag[0] ? ((const float*)src)[idx] : bf2f(((const unsigned short*)src)[idx]);
}

// ================= ARM A: 256x256, BK=64, simple 2-barrier, 1 blk/CU =======
// (round-4 structure + XCD-bijective swizzle)
template <int MODE>
__global__ __launch_bounds__(512, 2) void k_gemmA(
    const unsigned short* __restrict__ A, const unsigned short* __restrict__ B,
    const float* __restrict__ bias, void* __restrict__ Cv,
    int N, int K, int ldA, int ldB, int lb,
    long sAb, long sBb, long sCb, float scale,
    const int* __restrict__ flagp)
{
    extern __shared__ unsigned short lds_raw[];
    const int tid  = threadIdx.x;
    const int lane = tid & 63;
    const int wave = tid >> 6;
    const int nwg = gridDim.x * gridDim.y;
    const int bid = blockIdx.y * gridDim.x + blockIdx.x;
    const int vb  = (bid & 7) * (nwg >> 3) + (bid >> 3);
    const int bn  = (vb & (gridDim.x - 1)) * 256;
    const int bm  = (vb / gridDim.x) * 256;
    const int batch = bm >> lb;
    const int am0 = bm & ((1 << lb) - 1);
    const int Mb = 1 << lb;
    const unsigned short* Ab = A + (long)batch * sAb;
    const unsigned short* Bb = B + (long)batch * sBb;
    const long zC = (long)batch * sCb;
    const int wm = (wave >> 2) * 128;
    const int wn = (wave & 3) * 64;

    f32x4 acc[8][4];
    const f32x4 zero = {0.f, 0.f, 0.f, 0.f};
#pragma unroll
    for (int i = 0; i < 8; ++i)
#pragma unroll
        for (int j = 0; j < 4; ++j) acc[i][j] = zero;

    auto stage = [&](int kt, int cb) {
        unsigned short* LA = lds_raw + (size_t)cb * 32768;
        unsigned short* LB = LA + 16384;
#pragma unroll
        for (int j = 0; j < 4; ++j) {
            const int d = j * 512 + tid;
            const int row = d >> 3;
            const int klo = (d & 7) ^ (row & 7);
            gld16(Ab + (long)(am0 + row) * ldA + kt * 64 + klo * 8, LA + (size_t)d * 8);
            gld16(Bb + (long)(bn + row) * ldB + kt * 64 + klo * 8, LB + (size_t)d * 8);
        }
    };
    auto ctile = [&](int cb) {
        const unsigned short* LA = lds_raw + (size_t)cb * 32768;
        const unsigned short* LB = LA + 16384;
        b16x8 bfr[4][2];
#pragma unroll
        for (int p = 0; p < 4; ++p) {
            if (p == 0) {
#pragma unroll
                for (int j = 0; j < 4; ++j)
#pragma unroll
                    for (int s = 0; s < 2; ++s) {
                        const int r = wn + j * 16 + (lane & 15);
                        const int kl = s * 4 + (lane >> 4);
                        bfr[j][s] = *(const b16x8*)(LB + ((size_t)r * 8 + (kl ^ (r & 7))) * 8);
                    }
            }
            b16x8 a[2][2];
#pragma unroll
            for (int q = 0; q < 2; ++q)
#pragma unroll
                for (int s = 0; s < 2; ++s) {
                    const int r = wm + (2 * p + q) * 16 + (lane & 15);
                    const int kl = s * 4 + (lane >> 4);
                    a[q][s] = *(const b16x8*)(LA + ((size_t)r * 8 + (kl ^ (r & 7))) * 8);
                }
            __builtin_amdgcn_s_setprio(1);
#pragma unroll
            for (int q = 0; q < 2; ++q)
#pragma unroll
                for (int j = 0; j < 4; ++j)
#pragma unroll
                    for (int s = 0; s < 2; ++s)
                        acc[2 * p + q][j] = __builtin_amdgcn_mfma_f32_16x16x32_bf16(
                            a[q][s], bfr[j][s], acc[2 * p + q][j], 0, 0, 0);
            __builtin_amdgcn_s_setprio(0);
        }
    };

    const int NT = K >> 6;
    stage(0, 0);
    __syncthreads();
    int cur = 0;
    for (int kt = 0; kt < NT - 1; ++kt) {
        stage(kt + 1, cur ^ 1);
        ctile(cur);
        __syncthreads();
        cur ^= 1;
    }
    ctile(cur);

    const int fl = flagp ? flagp[0] : 1;
#pragma unroll
    for (int i = 0; i < 8; ++i)
#pragma unroll
        for (int j = 0; j < 4; ++j) {
            const int rloc = am0 + wm + i * 16 + (lane >> 4) * 4;
            const int n    = bn + wn + j * 16 + (lane & 15);
            const float bv = (MODE != 2 && bias != nullptr) ? bias[n] : 0.f;
            if (MODE == 0) {
                unsigned short* C = (unsigned short*)Cv;
#pragma unroll
                for (int r = 0; r < 4; ++r)
                    C[zC + (long)(rloc + r) * N + n] = f2bf(acc[i][j][r] * scale + bv);
            } else if (MODE == 1) {
                unsigned short* C = (unsigned short*)Cv;
                uint32_t p0 = f2bf(acc[i][j][0] * scale + bv) |
                              ((uint32_t)f2bf(acc[i][j][1] * scale + bv) << 16);
                uint32_t p1 = f2bf(acc[i][j][2] * scale + bv) |
                              ((uint32_t)f2bf(acc[i][j][3] * scale + bv) << 16);
                uint2 val; val.x = p0; val.y = p1;
                *(uint2*)(C + zC + (long)n * Mb + rloc) = val;
            } else if (MODE == 2) {
                float* C = (float*)Cv;
#pragma unroll
                for (int r = 0; r < 4; ++r)
                    C[zC + (long)(rloc + r) * N + n] = acc[i][j][r] * scale;
            } else {
                if (fl) {
                    float* C = (float*)Cv;
#pragma unroll
                    for (int r = 0; r < 4; ++r)
                        C[zC + (long)(rloc + r) * N + n] = acc[i][j][r] * scale + bv;
                } else {
                    unsigned short* C = (unsigned short*)Cv;
#pragma unroll
                    for (int r = 0; r < 4; ++r)
                        C[zC + (long)(rloc + r) * N + n] = f2bf(acc[i][j][r] * scale + bv);
                }
            }
        }
}

// ================= ARM B: 128x256, BK=32, 48KiB LDS, 2 blks/CU =============
// 8 waves (2M x 4N), wave-tile 64x64 (acc 64 f32). __launch_bounds__(512,4)
// caps VGPR at 128 -> 16 waves/CU when 2 blocks co-resident. Swizzle for
// BK=32 rows (4 chunks): klo' = klo ^ ((row>>1)&3)  -> 2-way free reads.
template <int MODE>
__global__ __launch_bounds__(512, 4) void k_gemmB(
    const unsigned short* __restrict__ A, const unsigned short* __restrict__ B,
    const float* __restrict__ bias, void* __restrict__ Cv,
    int N, int K, int ldA, int ldB, int lb,
    long sAb, long sBb, long sCb, float scale)
{
    extern __shared__ unsigned short lds_raw[];   // 2 bufs x (A 4096 + B 8192) shorts
    const int tid  = threadIdx.x;
    const int lane = tid & 63;
    const int wave = tid >> 6;
    const int nwg = gridDim.x * gridDim.y;
    const int bid = blockIdx.y * gridDim.x + blockIdx.x;
    const int vb  = (bid & 7) * (nwg >> 3) + (bid >> 3);
    const int bn  = (vb & (gridDim.x - 1)) * 256;
    const int bm  = (vb / gridDim.x) * 128;
    const int batch = bm >> lb;
    const int am0 = bm & ((1 << lb) - 1);
    const int Mb = 1 << lb;
    const unsigned short* Ab = A + (long)batch * sAb;
    const unsigned short* Bb = B + (long)batch * sBb;
    const long zC = (long)batch * sCb;
    const int wm = (wave >> 2) * 64;
    const int wn = (wave & 3) * 64;

    f32x4 acc[4][4];
    const f32x4 zero = {0.f, 0.f, 0.f, 0.f};
#pragma unroll
    for (int i = 0; i < 4; ++i)
#pragma unroll
        for (int j = 0; j < 4; ++j) acc[i][j] = zero;

    auto stage = [&](int kt, int cb) {
        unsigned short* Lb = lds_raw + (size_t)cb * 12288;
        {   // A: 512 chunks, 1/thread
            const int c = tid, row = c >> 2;
            const int klo = (c & 3) ^ ((row >> 1) & 3);
            gld16(Ab + (long)(am0 + row) * ldA + kt * 32 + klo * 8, Lb + (size_t)c * 8);
        }
#pragma unroll
        for (int j = 0; j < 2; ++j) {   // B: 1024 chunks, 2/thread
            const int c = j * 512 + tid, row = c >> 2;
            const int klo = (c & 3) ^ ((row >> 1) & 3);
            gld16(Bb + (long)(bn + row) * ldB + kt * 32 + klo * 8, Lb + 4096 + (size_t)c * 8);
        }
    };
    auto ctile = [&](int cb) {
        const unsigned short* LA = lds_raw + (size_t)cb * 12288;
        const unsigned short* LB = LA + 4096;
        const int kl = lane >> 4;
        b16x8 af[4], bf[4];
#pragma unroll
        for (int j = 0; j < 4; ++j) {
            const int r = wn + j * 16 + (lane & 15);
            bf[j] = *(const b16x8*)(LB + ((size_t)r * 4 + (kl ^ ((r >> 1) & 3))) * 8);
        }
#pragma unroll
        for (int i = 0; i < 4; ++i) {
            const int r = wm + i * 16 + (lane & 15);
            af[i] = *(const b16x8*)(LA + ((size_t)r * 4 + (kl ^ ((r >> 1) & 3))) * 8);
        }
        __builtin_amdgcn_s_setprio(1);
#pragma unroll
        for (int i = 0; i < 4; ++i)
#pragma unroll
            for (int j = 0; j < 4; ++j)
                acc[i][j] = __builtin_amdgcn_mfma_f32_16x16x32_bf16(af[i], bf[j], acc[i][j], 0, 0, 0);
        __builtin_amdgcn_s_setprio(0);
    };

    const int NT = K >> 5;
    stage(0, 0);
    __syncthreads();
    int cur = 0;
    for (int kt = 0; kt < NT - 1; ++kt) {
        stage(kt + 1, cur ^ 1);
        ctile(cur);
        __syncthreads();
        cur ^= 1;
    }
    ctile(cur);

#pragma unroll
    for (int i = 0; i < 4; ++i)
#pragma unroll
        for (int j = 0; j < 4; ++j) {
            const int rloc = am0 + wm + i * 16 + (lane >> 4) * 4;
            const int n    = bn + wn + j * 16 + (lane & 15);
            const float bv = (MODE != 2 && bias != nullptr) ? bias[n] : 0.f;
            if (MODE == 0) {
                unsigned short* C = (unsigned short*)Cv;
#pragma unroll
                for (int r = 0; r < 4; ++r)
                    C[zC + (long)(rloc + r) * N + n] = f2bf(acc[i][j][r] * scale + bv);
            } else if (MODE == 1) {
                unsigned short* C = (unsigned short*)Cv;
                uint32_t p0 = f2bf(acc[i][j][0] * scale + bv) |
                              ((uint32_t)f2bf(acc[i][j][1] * scale + bv) << 16);
                uint32_t p1 = f2bf(acc[i][j][2] * scale + bv) |
                              ((uint32_t)f2bf(acc[i][j][3] * scale + bv) << 16);
                uint2 val; val.x = p0; val.y = p1;
                *(uint2*)(C + zC + (long)n * Mb + rloc) = val;
            } else {
                float* C = (float*)Cv;
#pragma unroll
                for (int r = 0; r < 4; ++r)
                    C[zC + (long)(rloc + r) * N + n] = acc[i][j][r] * scale;
            }
        }
}

// ================= ARM C: 256x256, BK=64, counted-vmcnt 4-phase ============
// (round-5 structure, verbatim)
template <int MODE>
__global__ __launch_bounds__(512, 2) void k_gemmC(
    const unsigned short* __restrict__ A, const unsigned short* __restrict__ B,
    const float* __restrict__ bias, void* __restrict__ Cv,
    int N, int K, int ldA, int ldB, int lb,
    long sAb, long sBb, long sCb, float scale)
{
    extern __shared__ unsigned short lds_raw[];
    const int tid  = threadIdx.x;
    const int lane = tid & 63;
    const int wave = tid >> 6;
    const int nwg = gridDim.x * gridDim.y;
    const int bid = blockIdx.y * gridDim.x + blockIdx.x;
    const int vb  = (bid & 7) * (nwg >> 3) + (bid >> 3);
    const int bn  = (vb & (gridDim.x - 1)) * 256;
    const int bm  = (vb / gridDim.x) * 256;
    const int batch = bm >> lb;
    const int am0 = bm & ((1 << lb) - 1);
    const unsigned short* Ab = A + (long)batch * sAb;
    const unsigned short* Bb = B + (long)batch * sBb;
    const long zC = (long)batch * sCb;
    const int g  = wave >> 2;
    const int wn = (wave & 3) * 64;

    f32x4 acc[8][4];
    const f32x4 zero = {0.f, 0.f, 0.f, 0.f};
#pragma unroll
    for (int i = 0; i < 8; ++i)
#pragma unroll
        for (int j = 0; j < 4; ++j) acc[i][j] = zero;

    auto stageQ = [&](int kt, int cb, int q) {
        unsigned short* Lbase = lds_raw + (size_t)cb * 32768 + ((q < 2) ? 16384 : 0);
#pragma unroll
        for (int j = 0; j < 2; ++j) {
            const int c = (q & 1) * 1024 + j * 512 + tid;
            const int row = c >> 3;
            const int klo = (c & 7) ^ (row & 7);
            if (q < 2)
                gld16(Bb + (long)(bn + row) * ldB + kt * 64 + klo * 8, Lbase + (size_t)c * 8);
            else
                gld16(Ab + (long)(am0 + row) * ldA + kt * 64 + klo * 8, Lbase + (size_t)c * 8);
        }
    };

    const int NT = K >> 6;
#pragma unroll
    for (int q = 0; q < 4; ++q) stageQ(0, 0, q);

    int cur = 0;
    for (int t = 0; t < NT; ++t) {
        const int has_next = (t + 1 < NT);
        const unsigned short* LA = lds_raw + (size_t)cur * 32768;
        const unsigned short* LB = LA + 16384;
        b16x8 bfr[4][2];
#pragma unroll
        for (int p = 0; p < 4; ++p) {
            if (p == 0) {
                asm volatile("s_waitcnt vmcnt(2)" ::: "memory");
            } else if (p == 2) {
                if (has_next) asm volatile("s_waitcnt vmcnt(4)" ::: "memory");
                else          asm volatile("s_waitcnt vmcnt(0)" ::: "memory");
            }
            __builtin_amdgcn_sched_barrier(0);
            __builtin_amdgcn_s_barrier();
            asm volatile("" ::: "memory");
            if (p == 0) {
#pragma unroll
                for (int j = 0; j < 4; ++j)
#pragma unroll
                    for (int s = 0; s < 2; ++s) {
                        const int r = wn + j * 16 + (lane & 15);
                        const int kl = s * 4 + (lane >> 4);
                        bfr[j][s] = *(const b16x8*)(LB + ((size_t)r * 8 + (kl ^ (r & 7))) * 8);
                    }
            }
            b16x8 afr[2][2];
#pragma unroll
            for (int r = 0; r < 2; ++r)
#pragma unroll
                for (int s = 0; s < 2; ++s) {
                    const int row = (p >> 1) * 128 + (p & 1) * 64 + g * 32 + r * 16 + (lane & 15);
                    const int kl = s * 4 + (lane >> 4);
                    afr[r][s] = *(const b16x8*)(LA + ((size_t)row * 8 + (kl ^ (row & 7))) * 8);
                }
            if (has_next) stageQ(t + 1, cur ^ 1, p);
            asm volatile("" ::: "memory");
            __builtin_amdgcn_s_barrier();
            __builtin_amdgcn_sched_barrier(0);
            __builtin_amdgcn_s_setprio(1);
#pragma unroll
            for (int r = 0; r < 2; ++r)
#pragma unroll
                for (int j = 0; j < 4; ++j)
#pragma unroll
                    for (int s = 0; s < 2; ++s)
                        acc[p * 2 + r][j] = __builtin_amdgcn_mfma_f32_16x16x32_bf16(
                            afr[r][s], bfr[j][s], acc[p * 2 + r][j], 0, 0, 0);
            __builtin_amdgcn_s_setprio(0);
        }
        cur ^= 1;
    }

#pragma unroll
    for (int i = 0; i < 8; ++i) {
        const int p = i >> 1, r = i & 1;
        const int rloc = am0 + (p >> 1) * 128 + (p & 1) * 64 + g * 32 + r * 16 + (lane >> 4) * 4;
#pragma unroll
        for (int j = 0; j < 4; ++j) {
            const int n = bn + wn + j * 16 + (lane & 15);
            const float bv = (bias != nullptr) ? bias[n] : 0.f;
            unsigned short* C = (unsigned short*)Cv;
#pragma unroll
            for (int rr = 0; rr < 4; ++rr)
                C[zC + (long)(rloc + rr) * N + n] = f2bf(acc[i][j][rr] * scale + bv);
        }
    }
}

// ---------------- row softmax over 1024 cols, IN-PLACE ----------------
__global__ __launch_bounds__(256) void k_softmax(float* __restrict__ S) {
    const long row = blockIdx.x;
    float* s = S + row * 1024;
    unsigned short* p = (unsigned short*)s;
    const int tid = threadIdx.x;
    float4 v = ((const float4*)s)[tid];
    float m = fmaxf(fmaxf(v.x, v.y), fmaxf(v.z, v.w));
#pragma unroll
    for (int o = 32; o > 0; o >>= 1) m = fmaxf(m, __shfl_xor(m, o));
    __shared__ float sm[4], ss[4];
    if ((tid & 63) == 0) sm[tid >> 6] = m;
    __syncthreads();
    m = fmaxf(fmaxf(sm[0], sm[1]), fmaxf(sm[2], sm[3]));
    float e0 = __expf(v.x - m), e1 = __expf(v.y - m);
    float e2 = __expf(v.z - m), e3 = __expf(v.w - m);
    float sum = e0 + e1 + e2 + e3;
#pragma unroll
    for (int o = 32; o > 0; o >>= 1) sum += __shfl_xor(sum, o);
    if ((tid & 63) == 0) ss[tid >> 6] = sum;
    __syncthreads();
    float inv = 1.f / (ss[0] + ss[1] + ss[2] + ss[3]);
    uint32_t w0 = f2bf(e0 * inv) | ((uint32_t)f2bf(e1 * inv) << 16);
    uint32_t w1 = f2bf(e2 * inv) | ((uint32_t)f2bf(e3 * inv) << 16);
    uint2 val; val.x = w0; val.y = w1;
    *(uint2*)(p + tid * 4) = val;
}

// ---------------- host ----------------
extern "C" void kernel_launch(void* const* d_in, const int* in_sizes, int n_in,
                              void* d_out, int out_size, void* d_ws, size_t ws_size,
                              hipStream_t stream) {
    (void)in_sizes; (void)n_in; (void)out_size; (void)ws_size;
    const void* q_in = d_in[0];
    const void* k_in = d_in[1];
    const void* v_in = d_in[2];
    const void* Wq   = d_in[3];
    const void* bq   = d_in[4];
    const void* Wk   = d_in[5];
    const void* bk   = d_in[6];
    const void* Wv   = d_in[7];
    const void* bv   = d_in[8];
    const void* Wo   = d_in[9];
    const void* bo   = d_in[10];

    const size_t MB = 1u << 20;
    const size_t LDS_A = 131072, LDS_B = 49152;
    hipFuncSetAttribute((const void*)k_gemmA<0>, hipFuncAttributeMaxDynamicSharedMemorySize, (int)LDS_A);
    hipFuncSetAttribute((const void*)k_gemmA<2>, hipFuncAttributeMaxDynamicSharedMemorySize, (int)LDS_A);
    hipFuncSetAttribute((const void*)k_gemmA<3>, hipFuncAttributeMaxDynamicSharedMemorySize, (int)LDS_A);
    hipFuncSetAttribute((const void*)k_gemmB<1>, hipFuncAttributeMaxDynamicSharedMemorySize, (int)LDS_B);
    hipFuncSetAttribute((const void*)k_gemmC<0>, hipFuncAttributeMaxDynamicSharedMemorySize, (int)LDS_A);

    // workspace (97 MB proven): flag 1MB + R1(32) + R2(32) + R3(32)
    char* ws = (char*)d_ws;
    int*            flag = (int*)ws;
    unsigned short* R1   = (unsigned short*)(ws + 1 * MB);
    unsigned short* R2   = (unsigned short*)(ws + 33 * MB);
    char*           R3   = ws + 65 * MB;
    unsigned short* kb = R1, *qb = R1, *vb = R1;
    unsigned short* Kt = R2, *attn = R2;
    float*          scores = (float*)R1;
    unsigned short* P      = R1;                        // row i at i*2048 shorts
    unsigned short* wqb = (unsigned short*)R3;
    unsigned short* wkb = (unsigned short*)(R3 + 1 * MB);
    unsigned short* wvb = (unsigned short*)(R3 + 3 * MB);
    unsigned short* wob = (unsigned short*)(R3 + 5 * MB);
    float*          bias4 = (float*)(R3 + 7 * MB);
    unsigned short* Vp = (unsigned short*)d_out;
    unsigned short* Qt = (unsigned short*)((char*)d_out + 32 * MB);

    dim3 blk(256), blk5(512);
    k_detect<<<1, blk, 0, stream>>>((const unsigned short*)q_in, 4096, flag);
    k_cvt_bias<<<16, blk, 0, stream>>>(bq, bk, bv, bo, bias4, flag);
    k_cvt<<<256, blk, 0, stream>>>(Wq, wqb, 1024L * 512 / 8, flag);
    k_cvt<<<512, blk, 0, stream>>>(Wk, wkb, 1024L * 1024 / 8, flag);
    k_cvt<<<512, blk, 0, stream>>>(Wv, wvb, 1024L * 1024 / 8, flag);
    k_cvt<<<512, blk, 0, stream>>>(Wo, wob, 1024L * 1024 / 8, flag);

    // --- K path: ARM B (128x256, BK=32, 2 blk/CU), grid (4,128)=512 blocks
    k_cvt<<<2048, blk, 0, stream>>>(k_in, kb, 8L * 2048 * 1024 / 8, flag);
    k_gemmB<1><<<dim3(4, 128), blk5, LDS_B, stream>>>(
        kb, wkb, bias4 + 1024, Kt, 1024, 1024, 1024, 1024, 11,
        2048L * 1024, 0, 1024L * 2048, 1.f);
    // --- Q path: ARM B, grid (4,128), K=512
    k_cvt<<<2048, blk, 0, stream>>>(q_in, qb, 8L * 2048 * 512 / 8, flag);
    k_gemmB<1><<<dim3(4, 128), blk5, LDS_B, stream>>>(
        qb, wqb, bias4, Qt, 1024, 512, 512, 512, 11,
        2048L * 512, 0, 1024L * 2048, 1.f);
    // --- V path: ARM A, grid (4,64)
    k_cvt<<<2048, blk, 0, stream>>>(v_in, vb, 8L * 2048 * 1024 / 8, flag);
    k_gemmA<0><<<dim3(4, 64), blk5, LDS_A, stream>>>(
        vb, wvb, bias4 + 2 * 1024, Vp, 1024, 1024, 1024, 1024, 24,
        0, 0, 0, 1.f, nullptr);
    // --- scores: ARM A (f32 out), grid (4,32)
    k_gemmA<2><<<dim3(4, 32), blk5, LDS_A, stream>>>(
        Qt, Kt, nullptr, scores, 1024, 2048, 2048, 2048, 10,
        1024L * 2048, 1024L * 2048, 1024L * 1024, 0.125f, nullptr);
    // --- softmax in-place -> P
    k_softmax<<<dim3(8192), blk, 0, stream>>>(scores);
    // --- attn: ARM C (4-phase), grid (4,64)
    k_gemmC<0><<<dim3(4, 64), blk5, LDS_A, stream>>>(
        Vp, P, nullptr, attn, 1024, 1024, 1024, 2048, 11,
        2048L * 1024, 1024L * 2048, 2048L * 1024, 1.f);
    // --- out: ARM A (MODE 3), grid (4,64)
    k_gemmA<3><<<dim3(4, 64), blk5, LDS_A, stream>>>(
        attn, wob, bias4 + 3 * 1024, d_out, 1024, 1024, 1024, 1024, 24,
        0, 0, 0, 1.f, flag);
}